// Round 1
// baseline (1002.119 us; speedup 1.0000x reference)
//
#include <hip/hip_runtime.h>
#include <math.h>

// VQ-VAE quantize: per position argmax_n dot(z_p, W_n), z_q = W[ind], loss, ind.
// z: (8, 256, 32, 32) fp32 -> 8192 positions (b*1024 + h*32 + w) x 256 dims
// W: (8192, 256) fp32
// out: [z_q (2097152 fp32)] [loss (1 fp32)] [ind (8192 fp32-encoded ints)]

#define NE     8192
#define ED     256
#define TP     16      // positions per block
#define CHUNK  256     // codes per chunk
#define NCHUNK 32      // NE / CHUNK
#define KB     32      // k-panel dims
#define NKP    8       // ED / KB
#define ZPAD   260     // zs row stride (floats), mult of 4 for float4 align
#define WPAD   36      // ws row stride: lane stride 36 dwords -> bank-uniform b128

__global__ __launch_bounds__(256, 2)
void vq_kernel(const float* __restrict__ z, const float* __restrict__ W,
               float* __restrict__ zq, float* __restrict__ loss,
               float* __restrict__ ind)
{
    __shared__ float zs[TP * ZPAD];      // 16.6 KB: z tile [pos][dim]
    __shared__ float ws[CHUNK * WPAD];   // 36.9 KB: W panel [code][dim-panel]
    __shared__ int   best[TP];
    __shared__ float lred[4];

    const int t    = threadIdx.x;
    const int w    = t >> 6;    // wave id 0..3 -> owns positions w*4..w*4+3
    const int lane = t & 63;
    const int cg   = t & 63;    // code group within chunk
    const int pos_base = blockIdx.x * TP;
    const int b  = pos_base >> 10;
    const int s0 = pos_base & 1023;
    const float* zb = z + (size_t)b * 262144 + s0;

    // ---- stage z tile (coalesced 64B segments; 2-way LDS write = free) ----
    {
        int p = t & 15, dg = t >> 4;
        for (int i = 0; i < 16; ++i) {
            int d = i * 16 + dg;
            zs[p * ZPAD + d] = zb[(size_t)d * 1024 + p];
        }
    }

    float maxv[4];
    int   maxi[4];
#pragma unroll
    for (int i = 0; i < 4; ++i) { maxv[i] = -INFINITY; maxi[i] = 0; }

    for (int cc = 0; cc < NCHUNK; ++cc) {
        float acc[4][4];
#pragma unroll
        for (int i = 0; i < 4; ++i)
#pragma unroll
            for (int j = 0; j < 4; ++j) acc[i][j] = 0.0f;

        for (int kp = 0; kp < NKP; ++kp) {
            __syncthreads();  // previous panel fully consumed (also covers zs staging)
            // ---- stage W panel: 256 codes x 32 dims; bank-uniform writes ----
#pragma unroll
            for (int i = 0; i < 8; ++i) {
                int f = i * 256 + t;          // float4 id, 2048 total
                int code = f >> 3, k4 = f & 7;
                float4 v = *(const float4*)&W[(size_t)(cc * CHUNK + code) * ED + kp * KB + k4 * 4];
                *(float4*)&ws[code * WPAD + k4 * 4] = v;
            }
            __syncthreads();

#pragma unroll
            for (int k4 = 0; k4 < 8; ++k4) {
                float4 zf[4], wf[4];
#pragma unroll
                for (int i = 0; i < 4; ++i)   // wave-uniform addr -> broadcast (free)
                    zf[i] = *(const float4*)&zs[(w * 4 + i) * ZPAD + kp * KB + k4 * 4];
#pragma unroll
                for (int j = 0; j < 4; ++j)   // lane stride 36 dwords -> uniform banks
                    wf[j] = *(const float4*)&ws[(cg + 64 * j) * WPAD + k4 * 4];
#pragma unroll
                for (int i = 0; i < 4; ++i)
#pragma unroll
                    for (int j = 0; j < 4; ++j) {
                        acc[i][j] += zf[i].x * wf[j].x;
                        acc[i][j] += zf[i].y * wf[j].y;
                        acc[i][j] += zf[i].z * wf[j].z;
                        acc[i][j] += zf[i].w * wf[j].w;
                    }
            }
        }

        // ---- fold chunk logits into running argmax (first-index tie-break) ----
#pragma unroll
        for (int i = 0; i < 4; ++i)
#pragma unroll
            for (int j = 0; j < 4; ++j) {
                int code = cc * CHUNK + cg + 64 * j;
                float v = acc[i][j];
                if (v > maxv[i] || (v == maxv[i] && code < maxi[i])) {
                    maxv[i] = v; maxi[i] = code;
                }
            }
    }

    // ---- wave-level argmax reduction (positions w*4+i owned by wave w) ----
#pragma unroll
    for (int i = 0; i < 4; ++i) {
        float v = maxv[i];
        int   idx = maxi[i];
        for (int off = 32; off > 0; off >>= 1) {
            float ov = __shfl_down(v, off, 64);
            int   oi = __shfl_down(idx, off, 64);
            if (ov > v || (ov == v && oi < idx)) { v = ov; idx = oi; }
        }
        if (lane == 0) {
            int p = w * 4 + i;
            best[p] = idx;
            ind[pos_base + p] = (float)idx;   // out buffer read back as fp32
        }
    }
    __syncthreads();

    // ---- epilogue: z_q = W[ind], loss partial ----
    float lsum = 0.0f;
    for (int p = 0; p < TP; ++p) {
        int bi = best[p];
        float wv = W[(size_t)bi * ED + t];        // coalesced row read
        float zv = zs[p * ZPAD + t];              // stride-1: 2-way = free
        float dd = wv - zv;
        lsum += dd * dd;
        zq[(size_t)b * 262144 + (size_t)t * 1024 + s0 + p] = wv;
    }
    for (int off = 32; off > 0; off >>= 1) lsum += __shfl_down(lsum, off, 64);
    if (lane == 0) lred[w] = lsum;
    __syncthreads();
    if (t == 0) {
        float s = lred[0] + lred[1] + lred[2] + lred[3];
        // loss = (1 + 1 + BETA) * mean((W[ind]-z)^2), BETA=0.25, mean over 2097152
        atomicAdd(loss, s * (2.25f / 2097152.0f));
    }
}

extern "C" void kernel_launch(void* const* d_in, const int* in_sizes, int n_in,
                              void* d_out, int out_size, void* d_ws, size_t ws_size,
                              hipStream_t stream) {
    const float* z = (const float*)d_in[0];
    const float* W = (const float*)d_in[1];
    float* out  = (float*)d_out;
    float* zq   = out;
    float* loss = out + 2097152;
    float* ind  = out + 2097153;

    hipMemsetAsync(loss, 0, sizeof(float), stream);
    vq_kernel<<<512, 256, 0, stream>>>(z, W, zq, loss, ind);
}

// Round 2
// 206.137 us; speedup vs baseline: 4.8614x; 4.8614x over previous
//
#include <hip/hip_runtime.h>
#include <math.h>

// VQ-VAE quantize on MI355X.
// z: (8, 256, 32, 32) fp32 -> 8192 positions x 256 dims; W: (8192, 256) fp32.
// out: [z_q 2097152 fp32][loss 1 fp32][ind 8192 fp32-encoded ints]
//
// Pipeline: conv_w (W->bf16), conv_z (z->bf16 transposed [pos][k]),
// gemm_argmax (bf16 MFMA, fused top-2-candidate argmax -> ws partials),
// combine (margin-gated exact fp32 refine + z_q gather + loss).

using short8  = __attribute__((ext_vector_type(8))) short;   // 8 bf16, 4 VGPRs
using floatx4 = __attribute__((ext_vector_type(4))) float;   // MFMA acc

#define MARGIN 0.5f
#define APAD   264    // As row stride in shorts: 264*2B=528B, 16B-aligned, bank-uniform

__device__ inline unsigned short f2bf(float x) {
    union { float f; unsigned u; } v; v.f = x;
    unsigned r = v.u + 0x7fffu + ((v.u >> 16) & 1u);   // round-to-nearest-even
    return (unsigned short)(r >> 16);
}

// ---- pre-pass: W (8192x256) fp32 -> bf16, same layout (already [n][k]) ----
__global__ void conv_w_kernel(const float* __restrict__ W, unsigned short* __restrict__ wb) {
    int i = blockIdx.x * 256 + threadIdx.x;
    wb[i] = f2bf(W[i]);
}

// ---- pre-pass: z (b,d,s) fp32 -> zb[pos][d] bf16 via LDS tile transpose ----
__global__ void conv_z_kernel(const float* __restrict__ z, unsigned short* __restrict__ zb) {
    __shared__ float tile[64 * 65];
    int b  = blockIdx.x >> 6;
    int dt = (blockIdx.x >> 4) & 3;
    int st = blockIdx.x & 15;
    int dl = threadIdx.x >> 6, sl = threadIdx.x & 63;
#pragma unroll
    for (int i = 0; i < 16; ++i) {
        int d = i * 4 + dl;                       // 0..63 within d-tile
        tile[sl * 65 + d] = z[(size_t)b * 262144 + (size_t)(dt * 64 + d) * 1024 + st * 64 + sl];
    }
    __syncthreads();
    int d2 = threadIdx.x & 63, sr = threadIdx.x >> 6;
#pragma unroll
    for (int i = 0; i < 16; ++i) {
        int s = i * 4 + sr;
        int pos = b * 1024 + st * 64 + s;
        zb[(size_t)pos * 256 + dt * 64 + d2] = f2bf(tile[s * 65 + d2]);
    }
}

// ---- main: bf16 MFMA GEMM (128M x 1024N per block, K=256) + fused argmax ----
// grid (64 m-tiles, 8 n-splits), 256 thr. Wave tile 64x64, 16x16x32 MFMA.
// Per-lane running top-1 over its 32-code column subset; butterfly top-2 merge;
// partials: part[pos][bn*2+wn] = {v1, i1, v2, i2}.
__global__ __launch_bounds__(256, 2)
void gemm_argmax_kernel(const unsigned short* __restrict__ zb,
                        const unsigned short* __restrict__ wb,
                        float4* __restrict__ part)
{
    __shared__ unsigned short As[128 * APAD];   // 67.6 KB, full-K z tile (padded)
    __shared__ unsigned short Bs[128 * 32];     // 8 KB, W panel (unpadded: DMA dest)

    const int t  = threadIdx.x;
    const int bm = blockIdx.x, bn = blockIdx.y;
    const int w  = t >> 6, lane = t & 63;
    const int wm = w >> 1, wn = w & 1;
    const int q  = lane >> 4, l15 = lane & 15;

    // stage z tile once: 128 rows x 256 k (coalesced 512B row segments)
    {
        const unsigned short* src = zb + (size_t)bm * 128 * 256;
#pragma unroll
        for (int i = 0; i < 16; ++i) {
            int u = i * 256 + t;            // short8 unit, 4096 total
            int row = u >> 5, c8 = (u & 31) * 8;
            short8 v = *(const short8*)(src + row * 256 + c8);
            *(short8*)(&As[row * APAD + c8]) = v;
        }
    }

    float mv[4][4];
    int   mi[4][4];
#pragma unroll
    for (int im = 0; im < 4; ++im)
#pragma unroll
        for (int r = 0; r < 4; ++r) { mv[im][r] = -INFINITY; mi[im][r] = 0; }

    const unsigned short* wsrc = wb + (size_t)bn * 1024 * 256;

    for (int nc = 0; nc < 8; ++nc) {
        floatx4 acc[4][4];
#pragma unroll
        for (int im = 0; im < 4; ++im)
#pragma unroll
            for (int in = 0; in < 4; ++in) {
                floatx4 zz = {0.f, 0.f, 0.f, 0.f};
                acc[im][in] = zz;
            }

        for (int kp = 0; kp < 8; ++kp) {
            __syncthreads();   // Bs consumed (and, at iter 0, As staged)
            // async stage W panel: 128 codes x 32 k = 8 KB, width-16 DMA
#pragma unroll
            for (int i = 0; i < 2; ++i) {
                int u = i * 256 + t;
                int row = u >> 2, c8 = (u & 3) * 8;
                const unsigned short* g = wsrc + (size_t)(nc * 128 + row) * 256 + kp * 32 + c8;
                __builtin_amdgcn_global_load_lds(
                    (const __attribute__((address_space(1))) void*)g,
                    (__attribute__((address_space(3))) void*)(&Bs[u * 8]),
                    16, 0, 0);
            }
            __syncthreads();   // vmcnt drained by barrier semantics

            short8 af[4], bf[4];
#pragma unroll
            for (int im = 0; im < 4; ++im)
                af[im] = *(const short8*)(&As[(wm * 64 + im * 16 + l15) * APAD + kp * 32 + q * 8]);
#pragma unroll
            for (int in = 0; in < 4; ++in)
                bf[in] = *(const short8*)(&Bs[(wn * 64 + in * 16 + l15) * 32 + q * 8]);
#pragma unroll
            for (int im = 0; im < 4; ++im)
#pragma unroll
                for (int in = 0; in < 4; ++in)
                    acc[im][in] = __builtin_amdgcn_mfma_f32_16x16x32_bf16(
                        af[im], bf[in], acc[im][in], 0, 0, 0);
        }

        // fold 128-code chunk into per-lane running top-1 (ascending n => strict >)
#pragma unroll
        for (int im = 0; im < 4; ++im)
#pragma unroll
            for (int in = 0; in < 4; ++in) {
                int n = bn * 1024 + nc * 128 + wn * 64 + in * 16 + l15;
#pragma unroll
                for (int r = 0; r < 4; ++r) {
                    float v = acc[im][in][r];
                    if (v > mv[im][r]) { mv[im][r] = v; mi[im][r] = n; }
                }
            }
    }

    // butterfly top-2 merge across the 16 lanes sharing each m-row
#pragma unroll
    for (int im = 0; im < 4; ++im)
#pragma unroll
        for (int r = 0; r < 4; ++r) {
            float v1 = mv[im][r]; int i1 = mi[im][r];
            float v2 = -INFINITY; int i2 = 0x7FFFFFFF;
#pragma unroll
            for (int off = 1; off < 16; off <<= 1) {
                float o1 = __shfl_xor(v1, off, 64); int oi1 = __shfl_xor(i1, off, 64);
                float o2 = __shfl_xor(v2, off, 64); int oi2 = __shfl_xor(i2, off, 64);
                if (o1 > v1 || (o1 == v1 && oi1 < i1)) {
                    float tv = v1; int ti = i1; v1 = o1; i1 = oi1;
                    if (tv > o2 || (tv == o2 && ti < oi2)) { o2 = tv; oi2 = ti; }
                    // o2/oi2 now best remaining from the displaced pair
                }
                if (o2 > v2 || (o2 == v2 && oi2 < i2)) { v2 = o2; i2 = oi2; }
                if (o1 > v2 && !(o1 > v1 || (o1 == v1 && oi1 < i1))) { }  // (o1 already placed or < v1)
                else if (!(o1 == v1 && oi1 == i1)) { }
            }
            // note: the branchy merge above keeps top-2 of the union at every step
            if (l15 == 0) {
                int pos = bm * 128 + wm * 64 + im * 16 + q * 4 + r;
                float4 rec;
                rec.x = v1; rec.y = __int_as_float(i1);
                rec.z = v2; rec.w = __int_as_float(i2);
                part[(size_t)pos * 16 + bn * 2 + wn] = rec;
            }
        }
}

// ---- combine: exact-refine ambiguous argmax, write ind, z_q, loss ----
__global__ void combine_kernel(const float* __restrict__ z, const float* __restrict__ W,
                               const float4* __restrict__ part,
                               float* __restrict__ zq, float* __restrict__ loss,
                               float* __restrict__ ind)
{
    __shared__ int   best[64];
    __shared__ float lred[4];
    const int t = threadIdx.x, blk = blockIdx.x;
    const int pos0 = blk * 64;
    const int b = pos0 >> 10, s0 = pos0 & 1023;

    if (t < 64) {
        const int p = pos0 + t;
        float va[32]; int ia[32];
        float vmax = -INFINITY;
#pragma unroll
        for (int s = 0; s < 16; ++s) {
            float4 q4 = part[(size_t)p * 16 + s];
            va[2 * s]     = q4.x; ia[2 * s]     = __float_as_int(q4.y);
            va[2 * s + 1] = q4.z; ia[2 * s + 1] = __float_as_int(q4.w);
            vmax = fmaxf(vmax, fmaxf(q4.x, q4.z));
        }
        int cnt = 0;
#pragma unroll
        for (int k = 0; k < 32; ++k) cnt += (va[k] >= vmax - MARGIN) ? 1 : 0;
        int bi;
        if (cnt <= 1) {
            bi = 0x7FFFFFFF;
#pragma unroll
            for (int k = 0; k < 32; ++k) if (va[k] == vmax && ia[k] < bi) bi = ia[k];
        } else {
            // exact fp32 dot for each candidate (sequential-d order, np-compatible)
            const float* zp = z + (size_t)b * 262144 + (p & 1023);
            float bv = -INFINITY; bi = 0x7FFFFFFF;
            for (int k = 0; k < 32; ++k) {
                if (va[k] < vmax - MARGIN) continue;
                int c = ia[k];
                const float* wr = W + (size_t)c * 256;
                float dot = 0.f;
                for (int d = 0; d < 256; ++d) dot += zp[(size_t)d * 1024] * wr[d];
                if (dot > bv || (dot == bv && c < bi)) { bv = dot; bi = c; }
            }
        }
        best[t] = bi;
        ind[p] = (float)bi;
    }
    __syncthreads();

    float lsum = 0.f;
    for (int i = 0; i < 64; ++i) {
        int bi = best[i];
        float wv = W[(size_t)bi * 256 + t];                             // coalesced row
        float zv = z[(size_t)b * 262144 + (size_t)t * 1024 + s0 + i];
        float dd = wv - zv;
        lsum += dd * dd;
        zq[(size_t)b * 262144 + (size_t)t * 1024 + s0 + i] = wv;
    }
    for (int off = 32; off > 0; off >>= 1) lsum += __shfl_down(lsum, off, 64);
    if ((t & 63) == 0) lred[t >> 6] = lsum;
    __syncthreads();
    if (t == 0)
        atomicAdd(loss, (lred[0] + lred[1] + lred[2] + lred[3]) * (2.25f / 2097152.0f));
}

// ================= fallback (R1 fp32 kernel) if ws too small =================
#define TP 16
#define ZPAD 260
#define WPAD 36
__global__ __launch_bounds__(256, 2)
void vq_kernel(const float* __restrict__ z, const float* __restrict__ W,
               float* __restrict__ zq, float* __restrict__ loss,
               float* __restrict__ ind)
{
    __shared__ float zs[TP * ZPAD];
    __shared__ float ws[256 * WPAD];
    __shared__ int   best[TP];
    __shared__ float lred[4];
    const int t = threadIdx.x, w = t >> 6, lane = t & 63, cg = t & 63;
    const int pos_base = blockIdx.x * TP;
    const int b = pos_base >> 10, s0 = pos_base & 1023;
    const float* zb = z + (size_t)b * 262144 + s0;
    { int p = t & 15, dg = t >> 4;
      for (int i = 0; i < 16; ++i) { int d = i * 16 + dg; zs[p * ZPAD + d] = zb[(size_t)d * 1024 + p]; } }
    float maxv[4]; int maxi[4];
#pragma unroll
    for (int i = 0; i < 4; ++i) { maxv[i] = -INFINITY; maxi[i] = 0; }
    for (int cc = 0; cc < 32; ++cc) {
        float acc[4][4];
#pragma unroll
        for (int i = 0; i < 4; ++i)
#pragma unroll
            for (int j = 0; j < 4; ++j) acc[i][j] = 0.0f;
        for (int kp = 0; kp < 8; ++kp) {
            __syncthreads();
#pragma unroll
            for (int i = 0; i < 8; ++i) {
                int f = i * 256 + t, code = f >> 3, k4 = f & 7;
                float4 v = *(const float4*)&W[(size_t)(cc * 256 + code) * 256 + kp * 32 + k4 * 4];
                *(float4*)&ws[code * WPAD + k4 * 4] = v;
            }
            __syncthreads();
#pragma unroll
            for (int k4 = 0; k4 < 8; ++k4) {
                float4 zf[4], wf[4];
#pragma unroll
                for (int i = 0; i < 4; ++i) zf[i] = *(const float4*)&zs[(w * 4 + i) * ZPAD + kp * 32 + k4 * 4];
#pragma unroll
                for (int j = 0; j < 4; ++j) wf[j] = *(const float4*)&ws[(cg + 64 * j) * WPAD + k4 * 4];
#pragma unroll
                for (int i = 0; i < 4; ++i)
#pragma unroll
                    for (int j = 0; j < 4; ++j) {
                        acc[i][j] += zf[i].x * wf[j].x; acc[i][j] += zf[i].y * wf[j].y;
                        acc[i][j] += zf[i].z * wf[j].z; acc[i][j] += zf[i].w * wf[j].w;
                    }
            }
        }
#pragma unroll
        for (int i = 0; i < 4; ++i)
#pragma unroll
            for (int j = 0; j < 4; ++j) {
                int code = cc * 256 + cg + 64 * j; float v = acc[i][j];
                if (v > maxv[i] || (v == maxv[i] && code < maxi[i])) { maxv[i] = v; maxi[i] = code; }
            }
    }
#pragma unroll
    for (int i = 0; i < 4; ++i) {
        float v = maxv[i]; int idx = maxi[i];
        for (int off = 32; off > 0; off >>= 1) {
            float ov = __shfl_down(v, off, 64); int oi = __shfl_down(idx, off, 64);
            if (ov > v || (ov == v && oi < idx)) { v = ov; idx = oi; }
        }
        if (lane == 0) { int p = w * 4 + i; best[p] = idx; ind[pos_base + p] = (float)idx; }
    }
    __syncthreads();
    float lsum = 0.0f;
    for (int p = 0; p < TP; ++p) {
        int bi = best[p];
        float wv = W[(size_t)bi * 256 + t];
        float zv = zs[p * ZPAD + t];
        float dd = wv - zv; lsum += dd * dd;
        zq[(size_t)b * 262144 + (size_t)t * 1024 + s0 + p] = wv;
    }
    for (int off = 32; off > 0; off >>= 1) lsum += __shfl_down(lsum, off, 64);
    if (lane == 0) lred[w] = lsum;
    __syncthreads();
    if (t == 0) atomicAdd(loss, (lred[0] + lred[1] + lred[2] + lred[3]) * (2.25f / 2097152.0f));
}

extern "C" void kernel_launch(void* const* d_in, const int* in_sizes, int n_in,
                              void* d_out, int out_size, void* d_ws, size_t ws_size,
                              hipStream_t stream) {
    const float* z = (const float*)d_in[0];
    const float* W = (const float*)d_in[1];
    float* out  = (float*)d_out;
    float* zq   = out;
    float* loss = out + 2097152;
    float* ind  = out + 2097153;

    hipMemsetAsync(loss, 0, sizeof(float), stream);

    if (ws_size >= (size_t)10 * 1024 * 1024 + 65536) {
        unsigned short* zbuf = (unsigned short*)d_ws;                    // 4 MB
        unsigned short* wbuf = zbuf + 2097152;                           // 4 MB
        float4* part = (float4*)((char*)d_ws + (size_t)8 * 1024 * 1024); // 2 MB
        conv_w_kernel<<<8192, 256, 0, stream>>>(W, wbuf);
        conv_z_kernel<<<512, 256, 0, stream>>>(z, zbuf);
        gemm_argmax_kernel<<<dim3(64, 8), 256, 0, stream>>>(zbuf, wbuf, part);
        combine_kernel<<<128, 256, 0, stream>>>(z, W, part, zq, loss, ind);
    } else {
        vq_kernel<<<512, 256, 0, stream>>>(z, W, zq, loss, ind);
    }
}

// Round 3
// 161.229 us; speedup vs baseline: 6.2155x; 1.2785x over previous
//
#include <hip/hip_runtime.h>
#include <math.h>

// VQ-VAE quantize on MI355X.
// z: (8, 256, 32, 32) fp32 -> 8192 positions x 256 dims; W: (8192, 256) fp32.
// out: [z_q 2097152 fp32][loss 1 fp32][ind 8192 fp32-encoded ints]
//
// Pipeline: conv_w (W->bf16), conv_z (z->bf16 transposed [pos][k]),
// gemm_argmax (bf16 MFMA, fused per-lane top-1 + top-2 merge -> part[]),
// resolve (wave-per-position: margin-gated exact fp32 refine + z_q + loss).

using short8  = __attribute__((ext_vector_type(8))) short;   // 8 bf16, 4 VGPRs
using floatx4 = __attribute__((ext_vector_type(4))) float;   // MFMA acc

#define MARGIN 0.5f
#define APAD   264    // As row stride in shorts: 528B, 16B-aligned, 2-way banks

__device__ inline unsigned short f2bf(float x) {
    union { float f; unsigned u; } v; v.f = x;
    unsigned r = v.u + 0x7fffu + ((v.u >> 16) & 1u);   // round-to-nearest-even
    return (unsigned short)(r >> 16);
}

// ---- pre-pass: W (8192x256) fp32 -> bf16, same layout ----
__global__ void conv_w_kernel(const float* __restrict__ W, unsigned short* __restrict__ wb) {
    int i = blockIdx.x * 256 + threadIdx.x;
    float4 v = *(const float4*)&W[(size_t)i * 4];
    ushort4 o;
    o.x = f2bf(v.x); o.y = f2bf(v.y); o.z = f2bf(v.z); o.w = f2bf(v.w);
    *(ushort4*)&wb[(size_t)i * 4] = o;
}

// ---- pre-pass: z (b,d,s) fp32 -> zb[pos][d] bf16 via LDS tile transpose ----
__global__ void conv_z_kernel(const float* __restrict__ z, unsigned short* __restrict__ zb) {
    __shared__ float tile[64 * 65];
    int b  = blockIdx.x >> 6;
    int dt = (blockIdx.x >> 4) & 3;
    int st = blockIdx.x & 15;
    int dl = threadIdx.x >> 6, sl = threadIdx.x & 63;
#pragma unroll
    for (int i = 0; i < 16; ++i) {
        int d = i * 4 + dl;
        tile[sl * 65 + d] = z[(size_t)b * 262144 + (size_t)(dt * 64 + d) * 1024 + st * 64 + sl];
    }
    __syncthreads();
    int d2 = threadIdx.x & 63, sr = threadIdx.x >> 6;
#pragma unroll
    for (int i = 0; i < 16; ++i) {
        int s = i * 4 + sr;
        int pos = b * 1024 + st * 64 + s;
        zb[(size_t)pos * 256 + dt * 64 + d2] = f2bf(tile[s * 65 + d2]);
    }
}

// ---- main: bf16 MFMA GEMM (128M x 1024N per block, K=256) + fused argmax ----
// grid (64 m-tiles, 8 n-splits), 256 thr, wave tile 64x64, 16x16x32 MFMA.
// Bs XOR-swizzled: k-span q' of row n lives at shorts n*32 + 8*(q'^((n>>1)&3)).
__global__ __launch_bounds__(256, 2)
void gemm_argmax_kernel(const unsigned short* __restrict__ zb,
                        const unsigned short* __restrict__ wb,
                        float4* __restrict__ part)
{
    __shared__ unsigned short As[128 * APAD];   // 67.6 KB, full-K z tile
    __shared__ unsigned short Bs[128 * 32];     // 8 KB, W panel (DMA dest)

    const int t  = threadIdx.x;
    const int bm = blockIdx.x, bn = blockIdx.y;
    const int w  = t >> 6, lane = t & 63;
    const int wm = w >> 1, wn = w & 1;
    const int q  = lane >> 4, l15 = lane & 15;

    // stage z tile once: 128 rows x 256 k (coalesced 512B row segments)
    {
        const unsigned short* src = zb + (size_t)bm * 128 * 256;
#pragma unroll
        for (int i = 0; i < 16; ++i) {
            int u = i * 256 + t;
            int row = u >> 5, c8 = (u & 31) * 8;
            short8 v = *(const short8*)(src + row * 256 + c8);
            *(short8*)(&As[row * APAD + c8]) = v;
        }
    }

    float mv[4][4];
    int   mi[4][4];
#pragma unroll
    for (int im = 0; im < 4; ++im)
#pragma unroll
        for (int r = 0; r < 4; ++r) { mv[im][r] = -INFINITY; mi[im][r] = 0; }

    const unsigned short* wsrc = wb + (size_t)bn * 1024 * 256;

    for (int nc = 0; nc < 8; ++nc) {
        floatx4 acc[4][4];
#pragma unroll
        for (int im = 0; im < 4; ++im)
#pragma unroll
            for (int in = 0; in < 4; ++in) {
                floatx4 zz = {0.f, 0.f, 0.f, 0.f};
                acc[im][in] = zz;
            }

        for (int kp = 0; kp < 8; ++kp) {
            __syncthreads();   // Bs consumed (and, at iter 0, As staged)
            // async stage W panel, swizzled source so reads are bank-clean
#pragma unroll
            for (int i = 0; i < 2; ++i) {
                int u = i * 256 + t;
                int row = u >> 2, q2 = u & 3;
                int ksw = (q2 ^ ((row >> 1) & 3)) * 8;
                const unsigned short* g = wsrc + (size_t)(nc * 128 + row) * 256 + kp * 32 + ksw;
                __builtin_amdgcn_global_load_lds(
                    (const __attribute__((address_space(1))) void*)g,
                    (__attribute__((address_space(3))) void*)(&Bs[u * 8]),
                    16, 0, 0);
            }
            __syncthreads();

            short8 af[4], bf[4];
#pragma unroll
            for (int im = 0; im < 4; ++im)
                af[im] = *(const short8*)(&As[(wm * 64 + im * 16 + l15) * APAD + kp * 32 + q * 8]);
#pragma unroll
            for (int in = 0; in < 4; ++in) {
                int n32 = wn * 64 + in * 16 + l15;
                bf[in] = *(const short8*)(&Bs[n32 * 32 + (q ^ ((n32 >> 1) & 3)) * 8]);
            }
#pragma unroll
            for (int im = 0; im < 4; ++im)
#pragma unroll
                for (int in = 0; in < 4; ++in)
                    acc[im][in] = __builtin_amdgcn_mfma_f32_16x16x32_bf16(
                        af[im], bf[in], acc[im][in], 0, 0, 0);
        }

        // fold 128-code chunk into per-lane running top-1 (ascending n => strict >)
#pragma unroll
        for (int im = 0; im < 4; ++im)
#pragma unroll
            for (int in = 0; in < 4; ++in) {
                int n = bn * 1024 + nc * 128 + wn * 64 + in * 16 + l15;
#pragma unroll
                for (int r = 0; r < 4; ++r) {
                    float v = acc[im][in][r];
                    if (v > mv[im][r]) { mv[im][r] = v; mi[im][r] = n; }
                }
            }
    }

    // butterfly top-2 merge across the 16 lanes sharing each m-row
#pragma unroll
    for (int im = 0; im < 4; ++im)
#pragma unroll
        for (int r = 0; r < 4; ++r) {
            float v1 = mv[im][r]; int i1 = mi[im][r];
            float v2 = -INFINITY; int i2 = 0x7FFFFFFF;
#pragma unroll
            for (int off = 1; off < 16; off <<= 1) {
                float o1 = __shfl_xor(v1, off, 64); int oi1 = __shfl_xor(i1, off, 64);
                float o2 = __shfl_xor(v2, off, 64); int oi2 = __shfl_xor(i2, off, 64);
                if (o1 > v1 || (o1 == v1 && oi1 < i1)) {
                    float tv = v1; int ti = i1; v1 = o1; i1 = oi1;
                    if (tv > o2 || (tv == o2 && ti < oi2)) { o2 = tv; oi2 = ti; }
                }
                if (o2 > v2 || (o2 == v2 && oi2 < i2)) { v2 = o2; i2 = oi2; }
            }
            if (l15 == 0) {
                int pos = bm * 128 + wm * 64 + im * 16 + q * 4 + r;
                float4 rec;
                rec.x = v1; rec.y = __int_as_float(i1);
                rec.z = v2; rec.w = __int_as_float(i2);
                part[(size_t)pos * 16 + bn * 2 + wn] = rec;
            }
        }
}

// ---- resolve: one wave per position. Margin-gated exact fp32 refine,
//      then fused z_q gather-write + loss partial. ----
__global__ __launch_bounds__(256, 8)
void resolve_kernel(const float* __restrict__ z, const float* __restrict__ W,
                    const float4* __restrict__ part,
                    float* __restrict__ zq, float* __restrict__ loss,
                    float* __restrict__ ind)
{
    __shared__ float lred[4];
    const int t = threadIdx.x, w = t >> 6, lane = t & 63;
    const int p = blockIdx.x * 4 + w;
    const int b = p >> 10, s = p & 1023;

    // my 4 dims of z (exact fp32), stride-1024 gather (L2/L3 resident)
    const float* zp = z + (size_t)b * 262144 + s;
    float zf0 = zp[(size_t)(lane * 4 + 0) * 1024];
    float zf1 = zp[(size_t)(lane * 4 + 1) * 1024];
    float zf2 = zp[(size_t)(lane * 4 + 2) * 1024];
    float zf3 = zp[(size_t)(lane * 4 + 3) * 1024];

    // candidate records: slot = lane&15 (duplicated 4x, harmless)
    float4 rec = part[(size_t)p * 16 + (lane & 15)];
    float vmax = fmaxf(rec.x, rec.z);
#pragma unroll
    for (int off = 1; off < 64; off <<= 1)
        vmax = fmaxf(vmax, __shfl_xor(vmax, off, 64));
    const float thr = vmax - MARGIN;

    // count in-margin candidates (wave-uniform)
    int cloc = ((lane < 16) ? ((rec.x >= thr) ? 1 : 0) + ((rec.z >= thr) ? 1 : 0) : 0);
#pragma unroll
    for (int off = 1; off < 64; off <<= 1) cloc += __shfl_xor(cloc, off, 64);
    const int cnt = cloc;

    int bi;
    if (cnt <= 1) {
        // unambiguous: argmax of bf16 logits, min-index tie-break
        float bv = -INFINITY; bi = 0x7FFFFFFF;
#pragma unroll
        for (int s16 = 0; s16 < 16; ++s16) {
            float v1 = __shfl(rec.x, s16, 64); int i1 = __float_as_int(__shfl(rec.y, s16, 64));
            float v2 = __shfl(rec.z, s16, 64); int i2 = __float_as_int(__shfl(rec.w, s16, 64));
            if (v1 > bv || (v1 == bv && i1 < bi)) { bv = v1; bi = i1; }
            if (v2 > bv || (v2 == bv && i2 < bi)) { bv = v2; bi = i2; }
        }
    } else {
        // exact fp32 dot for each in-margin candidate (lane-parallel, coalesced W)
        float bv = -INFINITY; bi = 0x7FFFFFFF;
#pragma unroll
        for (int s16 = 0; s16 < 16; ++s16) {
            float vv[2]; int ii[2];
            vv[0] = __shfl(rec.x, s16, 64); ii[0] = __float_as_int(__shfl(rec.y, s16, 64));
            vv[1] = __shfl(rec.z, s16, 64); ii[1] = __float_as_int(__shfl(rec.w, s16, 64));
#pragma unroll
            for (int h = 0; h < 2; ++h) {
                if (vv[h] < thr) continue;           // wave-uniform
                int c = ii[h];
                float4 wf = *(const float4*)&W[(size_t)c * 256 + lane * 4];
                float d = zf0 * wf.x + zf1 * wf.y + zf2 * wf.z + zf3 * wf.w;
#pragma unroll
                for (int off = 1; off < 64; off <<= 1) d += __shfl_xor(d, off, 64);
                if (d > bv || (d == bv && c < bi)) { bv = d; bi = c; }
            }
        }
    }

    if (lane == 0) ind[p] = (float)bi;

    // fused epilogue: z_q = W[bi] (coalesced row read, strided dword stores),
    // loss partial from registers
    float4 wq = *(const float4*)&W[(size_t)bi * 256 + lane * 4];
    float* zqp = zq + (size_t)b * 262144 + s;
    zqp[(size_t)(lane * 4 + 0) * 1024] = wq.x;
    zqp[(size_t)(lane * 4 + 1) * 1024] = wq.y;
    zqp[(size_t)(lane * 4 + 2) * 1024] = wq.z;
    zqp[(size_t)(lane * 4 + 3) * 1024] = wq.w;

    float d0 = wq.x - zf0, d1 = wq.y - zf1, d2 = wq.z - zf2, d3 = wq.w - zf3;
    float ls = d0 * d0 + d1 * d1 + d2 * d2 + d3 * d3;
#pragma unroll
    for (int off = 1; off < 64; off <<= 1) ls += __shfl_xor(ls, off, 64);
    if (lane == 0) lred[w] = ls;
    __syncthreads();
    if (t == 0)
        atomicAdd(loss, (lred[0] + lred[1] + lred[2] + lred[3]) * (2.25f / 2097152.0f));
}

// ================= fallback (R1 fp32 kernel) if ws too small =================
#define TP 16
#define ZPAD 260
#define WPAD 36
__global__ __launch_bounds__(256, 2)
void vq_kernel(const float* __restrict__ z, const float* __restrict__ W,
               float* __restrict__ zq, float* __restrict__ loss,
               float* __restrict__ ind)
{
    __shared__ float zs[TP * ZPAD];
    __shared__ float ws[256 * WPAD];
    __shared__ int   best[TP];
    __shared__ float lred[4];
    const int t = threadIdx.x, w = t >> 6, lane = t & 63, cg = t & 63;
    const int pos_base = blockIdx.x * TP;
    const int b = pos_base >> 10, s0 = pos_base & 1023;
    const float* zb = z + (size_t)b * 262144 + s0;
    { int p = t & 15, dg = t >> 4;
      for (int i = 0; i < 16; ++i) { int d = i * 16 + dg; zs[p * ZPAD + d] = zb[(size_t)d * 1024 + p]; } }
    float maxv[4]; int maxi[4];
#pragma unroll
    for (int i = 0; i < 4; ++i) { maxv[i] = -INFINITY; maxi[i] = 0; }
    for (int cc = 0; cc < 32; ++cc) {
        float acc[4][4];
#pragma unroll
        for (int i = 0; i < 4; ++i)
#pragma unroll
            for (int j = 0; j < 4; ++j) acc[i][j] = 0.0f;
        for (int kp = 0; kp < 8; ++kp) {
            __syncthreads();
#pragma unroll
            for (int i = 0; i < 8; ++i) {
                int f = i * 256 + t, code = f >> 3, k4 = f & 7;
                float4 v = *(const float4*)&W[(size_t)(cc * 256 + code) * 256 + kp * 32 + k4 * 4];
                *(float4*)&ws[code * WPAD + k4 * 4] = v;
            }
            __syncthreads();
#pragma unroll
            for (int k4 = 0; k4 < 8; ++k4) {
                float4 zf[4], wf[4];
#pragma unroll
                for (int i = 0; i < 4; ++i) zf[i] = *(const float4*)&zs[(w * 4 + i) * ZPAD + kp * 32 + k4 * 4];
#pragma unroll
                for (int j = 0; j < 4; ++j) wf[j] = *(const float4*)&ws[(cg + 64 * j) * WPAD + k4 * 4];
#pragma unroll
                for (int i = 0; i < 4; ++i)
#pragma unroll
                    for (int j = 0; j < 4; ++j) {
                        acc[i][j] += zf[i].x * wf[j].x; acc[i][j] += zf[i].y * wf[j].y;
                        acc[i][j] += zf[i].z * wf[j].z; acc[i][j] += zf[i].w * wf[j].w;
                    }
            }
        }
#pragma unroll
        for (int i = 0; i < 4; ++i)
#pragma unroll
            for (int j = 0; j < 4; ++j) {
                int code = cc * 256 + cg + 64 * j; float v = acc[i][j];
                if (v > maxv[i] || (v == maxv[i] && code < maxi[i])) { maxv[i] = v; maxi[i] = code; }
            }
    }
#pragma unroll
    for (int i = 0; i < 4; ++i) {
        float v = maxv[i]; int idx = maxi[i];
        for (int off = 32; off > 0; off >>= 1) {
            float ov = __shfl_down(v, off, 64); int oi = __shfl_down(idx, off, 64);
            if (ov > v || (ov == v && oi < idx)) { v = ov; idx = oi; }
        }
        if (lane == 0) { int p = w * 4 + i; best[p] = idx; ind[pos_base + p] = (float)idx; }
    }
    __syncthreads();
    float lsum = 0.0f;
    for (int p = 0; p < TP; ++p) {
        int bi = best[p];
        float wv = W[(size_t)bi * 256 + t];
        float zv = zs[p * ZPAD + t];
        float dd = wv - zv; lsum += dd * dd;
        zq[(size_t)b * 262144 + (size_t)t * 1024 + s0 + p] = wv;
    }
    for (int off = 32; off > 0; off >>= 1) lsum += __shfl_down(lsum, off, 64);
    if (lane == 0) lred[w] = lsum;
    __syncthreads();
    if (t == 0) atomicAdd(loss, (lred[0] + lred[1] + lred[2] + lred[3]) * (2.25f / 2097152.0f));
}

extern "C" void kernel_launch(void* const* d_in, const int* in_sizes, int n_in,
                              void* d_out, int out_size, void* d_ws, size_t ws_size,
                              hipStream_t stream) {
    const float* z = (const float*)d_in[0];
    const float* W = (const float*)d_in[1];
    float* out  = (float*)d_out;
    float* zq   = out;
    float* loss = out + 2097152;
    float* ind  = out + 2097153;

    hipMemsetAsync(loss, 0, sizeof(float), stream);

    if (ws_size >= (size_t)10 * 1024 * 1024 + 65536) {
        unsigned short* zbuf = (unsigned short*)d_ws;                    // 4 MB
        unsigned short* wbuf = zbuf + 2097152;                           // 4 MB
        float4* part = (float4*)((char*)d_ws + (size_t)8 * 1024 * 1024); // 2 MB
        conv_w_kernel<<<2048, 256, 0, stream>>>(W, wbuf);
        conv_z_kernel<<<512, 256, 0, stream>>>(z, zbuf);
        gemm_argmax_kernel<<<dim3(64, 8), 256, 0, stream>>>(zbuf, wbuf, part);
        resolve_kernel<<<2048, 256, 0, stream>>>(z, W, part, zq, loss, ind);
    } else {
        vq_kernel<<<512, 256, 0, stream>>>(z, W, zq, loss, ind);
    }
}